// Round 3
// baseline (854.611 us; speedup 1.0000x reference)
//
#include <hip/hip_runtime.h>
#include <hip/hip_fp16.h>

#define N_NODES 50000
#define N_EDGES 800000
// F_KEY_NFEAT = 64, scale = 1/sqrt(64) = 0.125
// fiber2head: head h of a 64-float row = [f0[2h], f0[2h+1], f1[6h..6h+5]]

struct alignas(16) H8 { __half h[8]; };

// ---------- 1. logits + exp (f16, sequential write) + fused degree histogram ----------
__global__ __launch_bounds__(256) void k_logits(
    const float* __restrict__ k0, const float* __restrict__ k1,
    const float* __restrict__ q0, const float* __restrict__ q1,
    const int* __restrict__ ei, __half* __restrict__ e_buf,
    int* __restrict__ cnt_r, int* __restrict__ cnt_c)
{
    int e = blockIdx.x * blockDim.x + threadIdx.x;
    if (e >= N_EDGES) return;
    int row = ei[e];
    int col = ei[N_EDGES + e];

    // fire-and-forget histogram atomics (no return -> no dependent stall)
    atomicAdd(cnt_r + row, 1);
    atomicAdd(cnt_c + col, 1);

    const float4* k0v = (const float4*)(k0 + (size_t)e   * 16);
    const float4* q0v = (const float4*)(q0 + (size_t)col * 16);
    const float4* k1v = (const float4*)(k1 + (size_t)e   * 48);
    const float4* q1v = (const float4*)(q1 + (size_t)col * 48);

    float acc[8];
    #pragma unroll
    for (int h = 0; h < 8; ++h) acc[h] = 0.f;

    #pragma unroll
    for (int i = 0; i < 4; ++i) {
        float4 kv = k0v[i];
        float4 qv = q0v[i];
        acc[(4*i+0)/2] += kv.x * qv.x;
        acc[(4*i+1)/2] += kv.y * qv.y;
        acc[(4*i+2)/2] += kv.z * qv.z;
        acc[(4*i+3)/2] += kv.w * qv.w;
    }
    #pragma unroll
    for (int j = 0; j < 12; ++j) {
        float4 kv = k1v[j];
        float4 qv = q1v[j];
        acc[(4*j+0)/6] += kv.x * qv.x;
        acc[(4*j+1)/6] += kv.y * qv.y;
        acc[(4*j+2)/6] += kv.z * qv.z;
        acc[(4*j+3)/6] += kv.w * qv.w;
    }

    H8 pack;
    #pragma unroll
    for (int h = 0; h < 8; ++h) pack.h[h] = __float2half(__expf(acc[h] * 0.125f));
    *(H8*)(e_buf + (size_t)e * 8) = pack;
}

// ---------- 2. exclusive scan, one block per array, single sweep ----------
#define SCAN_T 1024
#define SCAN_C 49   // ceil(50000/1024)
__global__ __launch_bounds__(SCAN_T) void k_scan(int* __restrict__ cnt_r, int* __restrict__ off_r,
                                                 int* __restrict__ cnt_c, int* __restrict__ off_c)
{
    __shared__ int sm[SCAN_T];
    int* cnt = blockIdx.x ? cnt_c : cnt_r;
    int* off = blockIdx.x ? off_c : off_r;
    const int n = N_NODES;
    int t = threadIdx.x;
    int base = t * SCAN_C;

    int sum = 0;
    #pragma unroll 4
    for (int j = 0; j < SCAN_C; ++j) {
        int i = base + j;
        if (i < n) sum += cnt[i];
    }
    sm[t] = sum;
    __syncthreads();
    #pragma unroll
    for (int d = 1; d < SCAN_T; d <<= 1) {
        int v = (t >= d) ? sm[t - d] : 0;
        __syncthreads();
        sm[t] += v;
        __syncthreads();
    }
    int run = sm[t] - sum;   // exclusive prefix of this thread's chunk
    for (int j = 0; j < SCAN_C; ++j) {
        int i = base + j;
        if (i < n) {
            int v = cnt[i];
            off[i] = run;
            cnt[i] = run;    // becomes fill cursor
            run += v;
        }
    }
    if (t == 0) off[n] = sm[SCAN_T - 1];
}

// ---------- 3. CSR fill: 4 edges/thread, int atomic cursors + 4B scatters ----------
__global__ __launch_bounds__(256) void k_fill(const int* __restrict__ ei,
                                              int* __restrict__ cur_r, int* __restrict__ cur_c,
                                              int* __restrict__ eid_r, int* __restrict__ eid_c)
{
    int t = blockIdx.x * blockDim.x + threadIdx.x;
    int e4 = t * 4;
    if (e4 >= N_EDGES) return;
    int4 rows = *(const int4*)(ei + e4);
    int4 cols = *(const int4*)(ei + N_EDGES + e4);
    int r[4] = {rows.x, rows.y, rows.z, rows.w};
    int c[4] = {cols.x, cols.y, cols.z, cols.w};
    #pragma unroll
    for (int j = 0; j < 4; ++j) {
        int pr = atomicAdd(cur_r + r[j], 1);
        eid_r[pr] = e4 + j;
        int pc = atomicAdd(cur_c + c[j], 1);
        eid_c[pc] = e4 + j;
    }
}

// ---------- 4. softmax denominator: 1 thread/node, 16B vector gathers ----------
__global__ __launch_bounds__(256) void k_s(const __half* __restrict__ e_buf,
                                           const int* __restrict__ off_r,
                                           const int* __restrict__ eid_r,
                                           float* __restrict__ s)
{
    int node = blockIdx.x * blockDim.x + threadIdx.x;
    if (node >= N_NODES) return;
    int beg = off_r[node], end = off_r[node + 1];
    float acc[8];
    #pragma unroll
    for (int h = 0; h < 8; ++h) acc[h] = 0.f;
    for (int i = beg; i < end; ++i) {
        int eid = eid_r[i];
        H8 p = *(const H8*)(e_buf + (size_t)eid * 8);
        #pragma unroll
        for (int h = 0; h < 8; ++h) acc[h] += __half2float(p.h[h]);
    }
    float4* sv = (float4*)(s + (size_t)node * 8);
    sv[0] = make_float4(acc[0], acc[1], acc[2], acc[3]);
    sv[1] = make_float4(acc[4], acc[5], acc[6], acc[7]);
}

// ---------- 5. output via col-CSR gather: 1 wave/node, lane=feature ----------
__global__ __launch_bounds__(256) void k_out(
    const float* __restrict__ v0, const float* __restrict__ v1,
    const int* __restrict__ ei, const __half* __restrict__ e_buf,
    const float* __restrict__ s,
    const int* __restrict__ off_c, const int* __restrict__ eid_c,
    float* __restrict__ out0, float* __restrict__ out1)
{
    int wave = (blockIdx.x * blockDim.x + threadIdx.x) >> 6;
    int lane = threadIdx.x & 63;
    if (wave >= N_NODES) return;
    int node = wave;
    bool is0 = lane < 16;
    int f1 = lane - 16;
    int head = is0 ? (lane >> 1) : (f1 / 6);

    int beg = off_c[node], end = off_c[node + 1];
    float acc = 0.f;
    for (int i = beg; i < end; ++i) {
        int eid = eid_c[i];                   // wave-uniform
        int row = ei[eid];                    // wave-uniform
        float ev = __half2float(e_buf[(size_t)eid * 8 + head]);
        float sv = s[(size_t)row * 8 + head];
        float a = ev / sv;
        float v = is0 ? v0[(size_t)eid * 16 + lane]
                      : v1[(size_t)eid * 48 + f1];
        acc += a * v;
    }
    if (is0) out0[(size_t)node * 16 + lane] = acc;
    else     out1[(size_t)node * 48 + f1]   = acc;
}

extern "C" void kernel_launch(void* const* d_in, const int* in_sizes, int n_in,
                              void* d_out, int out_size, void* d_ws, size_t ws_size,
                              hipStream_t stream) {
    const float* v0 = (const float*)d_in[0];
    const float* v1 = (const float*)d_in[1];
    const float* k0 = (const float*)d_in[2];
    const float* k1 = (const float*)d_in[3];
    const float* q0 = (const float*)d_in[4];
    const float* q1 = (const float*)d_in[5];
    const int*   ei = (const int*)d_in[6];

    float* out0 = (float*)d_out;                      // N*16 floats
    float* out1 = out0 + (size_t)N_NODES * 16;        // N*48 floats

    // ---- workspace layout (bytes, 16B-aligned), total ~21.6 MB ----
    char* ws = (char*)d_ws;
    float*  s     = (float*) (ws + 0);                        // N*8*4    = 1,600,000
    __half* e_buf = (__half*)(ws + 1600000);                  // E*8*2    = 12,800,000
    int*    cnt_r = (int*)   (ws + 14400000);                 // N*4      = 200,000
    int*    cnt_c = (int*)   (ws + 14600000);                 // N*4      = 200,000
    int*    off_r = (int*)   (ws + 14800000);                 // (N+1)*4 -> pad 200,016
    int*    off_c = (int*)   (ws + 15000016);                 // pad 200,016
    int*    eid_r = (int*)   (ws + 15200032);                 // E*4      = 3,200,000
    int*    eid_c = (int*)   (ws + 18400032);                 // E*4      = 3,200,000

    hipMemsetAsync(cnt_r, 0, 400000, stream);   // cnt_r + cnt_c (adjacent)

    const int block = 256;
    const int gridE = (N_EDGES + block - 1) / block;

    k_logits<<<gridE, block, 0, stream>>>(k0, k1, q0, q1, ei, e_buf, cnt_r, cnt_c);
    k_scan<<<2, SCAN_T, 0, stream>>>(cnt_r, off_r, cnt_c, off_c);
    k_fill<<<(N_EDGES / 4 + block - 1) / block, block, 0, stream>>>(ei, cnt_r, cnt_c, eid_r, eid_c);
    k_s<<<(N_NODES + block - 1) / block, block, 0, stream>>>(e_buf, off_r, eid_r, s);
    k_out<<<(N_NODES * 64 + block - 1) / block, block, 0, stream>>>(
        v0, v1, ei, e_buf, s, off_c, eid_c, out0, out1);
}